// Round 2
// baseline (1081.173 us; speedup 1.0000x reference)
//
#include <hip/hip_runtime.h>
#include <hip/hip_bf16.h>
#include <math.h>

// ---------------- problem constants ----------------
#define T_TOKENS 8192          // B*S = 4*2048
#define D_MODEL  1024
#define N_EXP    8
#define I_RAW    2752
#define I_PAD    2816          // 88 * 32
#define N_CAT    5632          // 2 * I_PAD (gate/up interleaved in 32-blocks)
#define MAXROWS  18432         // 16384 + 8*256 (per-expert 256-alignment padding)
#define BK       32

typedef __attribute__((ext_vector_type(8))) short bf16x8;
typedef __attribute__((ext_vector_type(4))) float f32x4;
typedef unsigned short ushort_t;

// ctrl layout (ints): [0..7] counts, [8..15] cursor, [16..24] seg offsets
#define CTRL_COUNT 0
#define CTRL_CUR   8
#define CTRL_SEG   16

#define VMW(n)  asm volatile("s_waitcnt vmcnt(" n ")" ::: "memory")
#define BARRIER() asm volatile("s_barrier" ::: "memory")

__device__ __forceinline__ void gll16(const void* g, void* l) {
  __builtin_amdgcn_global_load_lds(
      (const __attribute__((address_space(1))) void*)g,
      (__attribute__((address_space(3))) void*)l, 16, 0, 0);
}

__device__ __forceinline__ float silu_mul(float g, float u) {
  return g / (1.f + __expf(-g)) * u;
}

// ---------------- router: one wave per token ----------------
__global__ void __launch_bounds__(64) router_kernel(
    const float* __restrict__ x, const float* __restrict__ rw,
    int* __restrict__ topidx, float* __restrict__ topw, int* __restrict__ ctrl) {
  const int t = blockIdx.x;
  const int lane = threadIdx.x;
  const float* xr = x + (size_t)t * D_MODEL;
  float acc[N_EXP];
#pragma unroll
  for (int e = 0; e < N_EXP; ++e) acc[e] = 0.f;
  for (int d = lane; d < D_MODEL; d += 64) {
    const float xv = xr[d];
    const float* r = rw + (size_t)d * N_EXP;
#pragma unroll
    for (int e = 0; e < N_EXP; ++e) acc[e] = fmaf(xv, r[e], acc[e]);
  }
#pragma unroll
  for (int e = 0; e < N_EXP; ++e) {
    for (int off = 32; off > 0; off >>= 1) acc[e] += __shfl_xor(acc[e], off, 64);
  }
  if (lane == 0) {
    float m = acc[0];
#pragma unroll
    for (int e = 1; e < N_EXP; ++e) m = fmaxf(m, acc[e]);
    float p[N_EXP], s = 0.f;
#pragma unroll
    for (int e = 0; e < N_EXP; ++e) { p[e] = expf(acc[e] - m); s += p[e]; }
    int i0 = 0; float v0 = p[0];
#pragma unroll
    for (int e = 1; e < N_EXP; ++e) if (p[e] > v0) { v0 = p[e]; i0 = e; }
    int i1 = -1; float v1 = -1.f;
#pragma unroll
    for (int e = 0; e < N_EXP; ++e) if (e != i0 && p[e] > v1) { v1 = p[e]; i1 = e; }
    v0 /= s; v1 /= s;
    const float r = v0 + v1 + 1e-6f;
    v0 /= r; v1 /= r;
    topidx[t * 2] = i0; topidx[t * 2 + 1] = i1;
    topw[t * 2] = v0;  topw[t * 2 + 1] = v1;
    atomicAdd(&ctrl[CTRL_COUNT + i0], 1);
    atomicAdd(&ctrl[CTRL_COUNT + i1], 1);
  }
}

// ---------------- x -> bf16 ----------------
__global__ void cvt_x_kernel(const float* __restrict__ x,
                             __hip_bfloat16* __restrict__ xb, int n4) {
  const int i = blockIdx.x * blockDim.x + threadIdx.x;
  if (i < n4) {
    const float4 v = ((const float4*)x)[i];
    __hip_bfloat16 b0 = __float2bfloat16(v.x), b1 = __float2bfloat16(v.y);
    __hip_bfloat16 b2 = __float2bfloat16(v.z), b3 = __float2bfloat16(v.w);
    ushort4 o;
    o.x = reinterpret_cast<ushort_t&>(b0); o.y = reinterpret_cast<ushort_t&>(b1);
    o.z = reinterpret_cast<ushort_t&>(b2); o.w = reinterpret_cast<ushort_t&>(b3);
    ((ushort4*)xb)[i] = o;
  }
}

// ---------------- transpose + convert with optional gate/up row remap --------
// mode 0: out[i][d] = in[d][i]   (row i = logical)
// mode 1: gate — out row n = (i>>5)*64 + (i&31)
// mode 2: up   — out row n = (i>>5)*64 + 32 + (i&31)
__global__ void __launch_bounds__(256) transpose_cvt_kernel(
    const float* __restrict__ in, __hip_bfloat16* __restrict__ out,
    int Ri, int Ci, int Co, long in_es, long out_es, int mode) {
  __shared__ float tile[32][33];
  const float* inp = in + (size_t)blockIdx.z * in_es;
  __hip_bfloat16* outp = out + (size_t)blockIdx.z * out_es;
  const int r0 = blockIdx.y * 32, c0 = blockIdx.x * 32;
  const int tx = threadIdx.x, ty = threadIdx.y;   // block (32,8)
#pragma unroll
  for (int i = 0; i < 4; ++i) {
    const int ir = ty + i * 8;
    const int grow = c0 + ir, gcol = r0 + tx;
    float v = (grow < Ri && gcol < Ci) ? inp[(size_t)grow * Ci + gcol] : 0.f;
    tile[ir][tx] = v;
  }
  __syncthreads();
#pragma unroll
  for (int i = 0; i < 4; ++i) {
    const int ilog = r0 + ty + i * 8;
    int orow;
    if (mode == 0) orow = ilog;
    else orow = ((ilog >> 5) << 6) + ((mode == 2) ? 32 : 0) + (ilog & 31);
    const int ocol = c0 + tx;
    outp[(size_t)orow * Co + ocol] = __float2bfloat16(tile[tx][ty + i * 8]);
  }
}

// ---------------- pad fill ----------------
__global__ void padfill_kernel(int* __restrict__ rowmap, float* __restrict__ roww) {
  const int i = blockIdx.x * blockDim.x + threadIdx.x;
  if (i < MAXROWS) { rowmap[i] = 0; roww[i] = 0.f; }
}

// ---------------- scan: 256-aligned segment offsets ----------------
__global__ void scan_kernel(int* __restrict__ ctrl) {
  if (threadIdx.x == 0 && blockIdx.x == 0) {
    int s = 0;
    ctrl[CTRL_SEG] = 0;
    for (int e = 0; e < N_EXP; ++e) {
      const int c = ctrl[CTRL_COUNT + e];
      s += (c + 255) & ~255;
      ctrl[CTRL_SEG + 1 + e] = s;
    }
  }
}

// ---------------- scatter ----------------
__global__ void scatter_kernel(const int* __restrict__ topidx, const float* __restrict__ topw,
                               int* __restrict__ ctrl, int* __restrict__ rowmap,
                               float* __restrict__ roww) {
  const int t = blockIdx.x * blockDim.x + threadIdx.x;
  if (t >= T_TOKENS) return;
#pragma unroll
  for (int k = 0; k < 2; ++k) {
    const int e = topidx[t * 2 + k];
    const int pos = ctrl[CTRL_SEG + e] + atomicAdd(&ctrl[CTRL_CUR + e], 1);
    rowmap[pos] = t * 2 + k;
    roww[pos] = topw[t * 2 + k];
  }
}

// =====================================================================
// GEMM1: 256x256 tile, BK=32, 4-deep LDS ring, counted vmcnt, 8 waves.
// A = gathered xb rows, B = wcat [E][N_CAT][D] (n-major, k contiguous).
// Epilogue: h = silu(gate)*up with gate=acc[mi][ni], up=acc[mi][ni+2].
// =====================================================================
__global__ void __launch_bounds__(512, 2) gemm1_kernel(
    const __hip_bfloat16* __restrict__ xb,
    const __hip_bfloat16* __restrict__ wcat,
    __hip_bfloat16* __restrict__ H,
    const int* __restrict__ rowmap, const int* __restrict__ ctrl) {
  const int e = blockIdx.z;
  const int s0 = ctrl[CTRL_SEG + e], s1 = ctrl[CTRL_SEG + e + 1];
  const int mbase = blockIdx.y * 256;
  if (mbase >= s1 - s0) return;
  const int nbase = blockIdx.x * 256;
  const int tid = threadIdx.x, lane = tid & 63, wid = tid >> 6;
  const int wrm = (wid >> 2) * 128, wrn = (wid & 3) * 64;

  __shared__ __align__(16) __hip_bfloat16 sA[4][256 * BK];
  __shared__ __align__(16) __hip_bfloat16 sB[4][256 * BK];

  // staging: thread covers rows tid>>2 and 128+(tid>>2), k-chunk (tid&3)*8
  const int srow0 = tid >> 2;
  const int skc = (tid & 3) * 8;
  const int tok0 = rowmap[s0 + mbase + srow0] >> 1;
  const int tok1 = rowmap[s0 + mbase + 128 + srow0] >> 1;
  const __hip_bfloat16* gA0 = xb + (size_t)tok0 * D_MODEL + skc;
  const __hip_bfloat16* gA1 = xb + (size_t)tok1 * D_MODEL + skc;
  const __hip_bfloat16* gB0 = wcat + ((size_t)e * N_CAT + nbase + srow0) * D_MODEL + skc;
  const __hip_bfloat16* gB1 = gB0 + (size_t)128 * D_MODEL;

  auto stage = [&](int buf, int kt) {
    const int ko = kt * BK;
    gll16(gA0 + ko, &sA[buf][tid * 8]);
    gll16(gA1 + ko, &sA[buf][4096 + tid * 8]);
    gll16(gB0 + ko, &sB[buf][tid * 8]);
    gll16(gB1 + ko, &sB[buf][4096 + tid * 8]);
  };

  f32x4 acc[8][4];
  const f32x4 z4 = {0.f, 0.f, 0.f, 0.f};
#pragma unroll
  for (int a = 0; a < 8; ++a)
#pragma unroll
    for (int b = 0; b < 4; ++b) acc[a][b] = z4;

  const int aoff = (wrm + (lane & 15)) * BK + (lane >> 4) * 8;
  const int boff = (wrn + (lane & 15)) * BK + (lane >> 4) * 8;

  auto compute = [&](int t) {
    const int cb = t & 3;
    const __hip_bfloat16* pa = &sA[cb][0];
    const __hip_bfloat16* pb = &sB[cb][0];
    bf16x8 a[8], b[4];
#pragma unroll
    for (int mi = 0; mi < 8; ++mi)
      a[mi] = *(const bf16x8*)&pa[aoff + mi * 16 * BK];
#pragma unroll
    for (int ni = 0; ni < 4; ++ni)
      b[ni] = *(const bf16x8*)&pb[boff + ni * 16 * BK];
    __builtin_amdgcn_s_setprio(1);
#pragma unroll
    for (int mi = 0; mi < 8; ++mi)
#pragma unroll
      for (int ni = 0; ni < 4; ++ni)
        acc[mi][ni] = __builtin_amdgcn_mfma_f32_16x16x32_bf16(a[mi], b[ni], acc[mi][ni], 0, 0, 0);
    __builtin_amdgcn_s_setprio(0);
  };

  const int NT = D_MODEL / BK;  // 32
  stage(0, 0); stage(1, 1); stage(2, 2);

  int t = 0;
  for (; t < NT - 3; ++t) {          // t = 0 .. NT-4
    VMW("8"); BARRIER();
    stage((t + 3) & 3, t + 3);
    compute(t);
  }
  { VMW("8"); BARRIER(); compute(NT - 3); }
  { VMW("4"); BARRIER(); compute(NT - 2); }
  { VMW("0"); BARRIER(); compute(NT - 1); }

  // epilogue: pair gate (ni 0,1) with up (ni 2,3); H col = g*32 + ni*16 + (lane&15)
  const int hcolbase = ((nbase + wrn) >> 6) * 32;
#pragma unroll
  for (int mi = 0; mi < 8; ++mi) {
    const int r0 = wrm + mi * 16 + ((lane >> 4) * 4);
#pragma unroll
    for (int ni = 0; ni < 2; ++ni) {
      const int hcol = hcolbase + ni * 16 + (lane & 15);
      const f32x4 g = acc[mi][ni], u = acc[mi][ni + 2];
#pragma unroll
      for (int j = 0; j < 4; ++j) {
        const float h = silu_mul(g[j], u[j]);
        H[(size_t)(s0 + mbase + r0 + j) * I_PAD + hcol] = __float2bfloat16(h);
      }
    }
  }
}

// =====================================================================
// GEMM2: out[tok] += w * (H @ Wd).  Same pipeline; K = I_PAD = 2816.
// =====================================================================
__global__ void __launch_bounds__(512, 2) gemm2_kernel(
    const __hip_bfloat16* __restrict__ H,
    const __hip_bfloat16* __restrict__ wdt,   // [E][D][I_PAD] n-major
    float* __restrict__ out,
    const int* __restrict__ rowmap, const float* __restrict__ roww,
    const int* __restrict__ ctrl) {
  const int e = blockIdx.z;
  const int s0 = ctrl[CTRL_SEG + e], s1 = ctrl[CTRL_SEG + e + 1];
  const int mbase = blockIdx.y * 256;
  if (mbase >= s1 - s0) return;
  const int nbase = blockIdx.x * 256;
  const int tid = threadIdx.x, lane = tid & 63, wid = tid >> 6;
  const int wrm = (wid >> 2) * 128, wrn = (wid & 3) * 64;

  __shared__ __align__(16) __hip_bfloat16 sA[4][256 * BK];
  __shared__ __align__(16) __hip_bfloat16 sB[4][256 * BK];
  __shared__ int sTok[256];
  __shared__ float sW[256];

  if (tid < 256) {
    sTok[tid] = rowmap[s0 + mbase + tid] >> 1;
    sW[tid] = roww[s0 + mbase + tid];
  }

  const int srow0 = tid >> 2;
  const int skc = (tid & 3) * 8;
  const __hip_bfloat16* gA0 = H + (size_t)(s0 + mbase + srow0) * I_PAD + skc;
  const __hip_bfloat16* gA1 = gA0 + (size_t)128 * I_PAD;
  const __hip_bfloat16* gB0 = wdt + ((size_t)e * D_MODEL + nbase + srow0) * I_PAD + skc;
  const __hip_bfloat16* gB1 = gB0 + (size_t)128 * I_PAD;

  auto stage = [&](int buf, int kt) {
    const int ko = kt * BK;
    gll16(gA0 + ko, &sA[buf][tid * 8]);
    gll16(gA1 + ko, &sA[buf][4096 + tid * 8]);
    gll16(gB0 + ko, &sB[buf][tid * 8]);
    gll16(gB1 + ko, &sB[buf][4096 + tid * 8]);
  };

  f32x4 acc[8][4];
  const f32x4 z4 = {0.f, 0.f, 0.f, 0.f};
#pragma unroll
  for (int a = 0; a < 8; ++a)
#pragma unroll
    for (int b = 0; b < 4; ++b) acc[a][b] = z4;

  const int aoff = (wrm + (lane & 15)) * BK + (lane >> 4) * 8;
  const int boff = (wrn + (lane & 15)) * BK + (lane >> 4) * 8;

  auto compute = [&](int t) {
    const int cb = t & 3;
    const __hip_bfloat16* pa = &sA[cb][0];
    const __hip_bfloat16* pb = &sB[cb][0];
    bf16x8 a[8], b[4];
#pragma unroll
    for (int mi = 0; mi < 8; ++mi)
      a[mi] = *(const bf16x8*)&pa[aoff + mi * 16 * BK];
#pragma unroll
    for (int ni = 0; ni < 4; ++ni)
      b[ni] = *(const bf16x8*)&pb[boff + ni * 16 * BK];
    __builtin_amdgcn_s_setprio(1);
#pragma unroll
    for (int mi = 0; mi < 8; ++mi)
#pragma unroll
      for (int ni = 0; ni < 4; ++ni)
        acc[mi][ni] = __builtin_amdgcn_mfma_f32_16x16x32_bf16(a[mi], b[ni], acc[mi][ni], 0, 0, 0);
    __builtin_amdgcn_s_setprio(0);
  };

  const int NT = I_PAD / BK;  // 88
  stage(0, 0); stage(1, 1); stage(2, 2);

  int t = 0;
  for (; t < NT - 3; ++t) {
    VMW("8"); BARRIER();
    stage((t + 3) & 3, t + 3);
    compute(t);
  }
  { VMW("8"); BARRIER(); compute(NT - 3); }
  { VMW("4"); BARRIER(); compute(NT - 2); }
  { VMW("0"); BARRIER(); compute(NT - 1); }

#pragma unroll
  for (int mi = 0; mi < 8; ++mi) {
    const int r0 = wrm + mi * 16 + ((lane >> 4) * 4);
#pragma unroll
    for (int ni = 0; ni < 4; ++ni) {
      const int col = nbase + wrn + ni * 16 + (lane & 15);
#pragma unroll
      for (int j = 0; j < 4; ++j) {
        const int lr = r0 + j;
        const float v = acc[mi][ni][j] * sW[lr];
        atomicAdd(&out[(size_t)sTok[lr] * D_MODEL + col], v);
      }
    }
  }
}

// ---------------- launch ----------------
extern "C" void kernel_launch(void* const* d_in, const int* in_sizes, int n_in,
                              void* d_out, int out_size, void* d_ws, size_t ws_size,
                              hipStream_t stream) {
  (void)in_sizes; (void)n_in; (void)ws_size;
  const float* x  = (const float*)d_in[0];
  const float* rw = (const float*)d_in[1];
  const float* wg = (const float*)d_in[2];
  const float* wu = (const float*)d_in[3];
  const float* wd = (const float*)d_in[4];
  float* out = (float*)d_out;

  char* ws = (char*)d_ws;
  size_t off = 0;
  auto alloc = [&](size_t bytes) -> char* {
    char* p = ws + off;
    off += (bytes + 255) & ~(size_t)255;
    return p;
  };

  int*   ctrl   = (int*)alloc(256);
  int*   topidx = (int*)alloc((size_t)T_TOKENS * 2 * 4);
  float* topw   = (float*)alloc((size_t)T_TOKENS * 2 * 4);
  int*   rowmap = (int*)alloc((size_t)MAXROWS * 4);
  float* roww   = (float*)alloc((size_t)MAXROWS * 4);
  __hip_bfloat16* xb   = (__hip_bfloat16*)alloc((size_t)T_TOKENS * D_MODEL * 2);
  __hip_bfloat16* wcat = (__hip_bfloat16*)alloc((size_t)N_EXP * N_CAT * D_MODEL * 2);
  __hip_bfloat16* Hbuf = (__hip_bfloat16*)alloc((size_t)MAXROWS * I_PAD * 2);
  // wdt aliases wcat (wcat dead after gemm1; wdt transpose runs after gemm1)
  __hip_bfloat16* wdt = wcat;

  hipMemsetAsync(ctrl, 0, 256, stream);
  hipMemsetAsync(out, 0, (size_t)out_size * 4, stream);

  cvt_x_kernel<<<(T_TOKENS * D_MODEL / 4 + 255) / 256, 256, 0, stream>>>(
      x, xb, T_TOKENS * D_MODEL / 4);

  dim3 tb(32, 8);
  // wg [E][1024][2752] -> wcat gate rows; wu -> wcat up rows
  transpose_cvt_kernel<<<dim3(D_MODEL / 32, I_PAD / 32, N_EXP), tb, 0, stream>>>(
      wg, wcat, D_MODEL, I_RAW, D_MODEL, (long)D_MODEL * I_RAW, (long)N_CAT * D_MODEL, 1);
  transpose_cvt_kernel<<<dim3(D_MODEL / 32, I_PAD / 32, N_EXP), tb, 0, stream>>>(
      wu, wcat, D_MODEL, I_RAW, D_MODEL, (long)D_MODEL * I_RAW, (long)N_CAT * D_MODEL, 2);

  router_kernel<<<T_TOKENS, 64, 0, stream>>>(x, rw, topidx, topw, ctrl);
  padfill_kernel<<<(MAXROWS + 255) / 256, 256, 0, stream>>>(rowmap, roww);
  scan_kernel<<<1, 64, 0, stream>>>(ctrl);
  scatter_kernel<<<(T_TOKENS + 255) / 256, 256, 0, stream>>>(topidx, topw, ctrl, rowmap, roww);

  gemm1_kernel<<<dim3(N_CAT / 256, 64, N_EXP), 512, 0, stream>>>(
      xb, wcat, Hbuf, rowmap, ctrl);

  // wd [E][2752][1024] -> wdt [E][1024][2816]  (into wcat's space, after gemm1)
  transpose_cvt_kernel<<<dim3(I_PAD / 32, D_MODEL / 32, N_EXP), tb, 0, stream>>>(
      wd, wdt, I_RAW, D_MODEL, I_PAD, (long)I_RAW * D_MODEL, (long)D_MODEL * I_PAD, 0);

  gemm2_kernel<<<dim3(D_MODEL / 256, 64, N_EXP), 512, 0, stream>>>(
      Hbuf, wdt, out, rowmap, roww, ctrl);
}